// Round 1
// baseline (178.641 us; speedup 1.0000x reference)
//
#include <hip/hip_runtime.h>

typedef _Float16 f16;
typedef _Float16 f16x8 __attribute__((ext_vector_type(8)));
typedef float f32x4 __attribute__((ext_vector_type(4)));

__device__ inline f32x4 mfma16(f16x8 a, f16x8 b, f32x4 c) {
    return __builtin_amdgcn_mfma_f32_16x16x32_f16(a, b, c, 0, 0, 0);
}

// ---------------------------------------------------------------------------
// Kernel 1: weight norm.  w[o,c] = g[o] * v[o,c] / ||v[o,:]||   (f16 output)
// ---------------------------------------------------------------------------
__global__ __launch_bounds__(256) void compute_w_k(const float* __restrict__ pv,
                                                   const float* __restrict__ pg,
                                                   f16* __restrict__ w) {
    int o = blockIdx.x;
    const float* row = pv + (size_t)o * 512;
    float s = 0.f;
    for (int c = threadIdx.x; c < 512; c += 256) { float t = row[c]; s += t * t; }
    for (int off = 32; off; off >>= 1) s += __shfl_down(s, off, 64);
    __shared__ float red[4];
    int lane = threadIdx.x & 63, wid = threadIdx.x >> 6;
    if (lane == 0) red[wid] = s;
    __syncthreads();
    float tot = red[0] + red[1] + red[2] + red[3];
    float scale = pg[o] * rsqrtf(tot);
    for (int c = threadIdx.x; c < 512; c += 256)
        w[(size_t)o * 512 + c] = (f16)(row[c] * scale);
}

// ---------------------------------------------------------------------------
// Kernel 2: transpose x (B,C,N) fp32 -> xT (B,N,C) f16, LDS 32x32 tiles
// ---------------------------------------------------------------------------
__global__ __launch_bounds__(256) void transpose_x_k(const float* __restrict__ x,
                                                     f16* __restrict__ xT) {
    __shared__ float t[32][33];
    int b = blockIdx.z, n0 = blockIdx.x * 32, c0 = blockIdx.y * 32;
    int tx = threadIdx.x, ty = threadIdx.y;  // 32 x 8
    const float* xb = x + (size_t)b * 512 * 1024;
    for (int i = 0; i < 4; i++)
        t[ty + 8 * i][tx] = xb[(size_t)(c0 + ty + 8 * i) * 1024 + n0 + tx];
    __syncthreads();
    f16* xTb = xT + (size_t)b * 1024 * 512;
    for (int i = 0; i < 4; i++)
        xTb[(size_t)(n0 + ty + 8 * i) * 512 + c0 + tx] = (f16)t[tx][ty + 8 * i];
}

// ---------------------------------------------------------------------------
// Kernel 3: QKV projection GEMM.  C[b][o,n] = sum_c w[o,c] * xT[b][n,c] + pb[o]
//   M=1536 (o), N=1024 (n), K=512 (c).  128x128x32 tiles, 4 waves, 64x64/wave.
//   Epilogue scatters:  sel<2 -> qk[b][sel][h][n][d],   sel==2 -> v[b][h][d][n]
// ---------------------------------------------------------------------------
#define GLDA 40  // 32 + 8 pad (f16 elems)
__global__ __launch_bounds__(256) void qkv_gemm_k(const f16* __restrict__ w,
                                                  const f16* __restrict__ xT,
                                                  const float* __restrict__ pb,
                                                  f16* __restrict__ qk,
                                                  f16* __restrict__ v) {
    __shared__ f16 lA[128 * GLDA];
    __shared__ f16 lB[128 * GLDA];
    int b = blockIdx.z;
    int oBase = blockIdx.y * 128;
    int nBase = blockIdx.x * 128;
    const f16* xb = xT + (size_t)b * 1024 * 512;
    int tid = threadIdx.x;
    int lane = tid & 63, warp = tid >> 6;
    int wy = warp >> 1, wx = warp & 1;
    int quad = lane >> 4, l15 = lane & 15;

    f32x4 acc[4][4] = {};

    for (int k0 = 0; k0 < 512; k0 += 32) {
        __syncthreads();
        for (int c = tid; c < 512; c += 256) {
            int row = c >> 2, col = (c & 3) * 8;
            *(f16x8*)&lA[row * GLDA + col] =
                *(const f16x8*)&w[(size_t)(oBase + row) * 512 + k0 + col];
            *(f16x8*)&lB[row * GLDA + col] =
                *(const f16x8*)&xb[(size_t)(nBase + row) * 512 + k0 + col];
        }
        __syncthreads();
        f16x8 af[4], bf[4];
        for (int mi = 0; mi < 4; mi++)
            af[mi] = *(f16x8*)&lA[(wy * 64 + mi * 16 + l15) * GLDA + quad * 8];
        for (int ni = 0; ni < 4; ni++)
            bf[ni] = *(f16x8*)&lB[(wx * 64 + ni * 16 + l15) * GLDA + quad * 8];
        for (int mi = 0; mi < 4; mi++)
            for (int ni = 0; ni < 4; ni++)
                acc[mi][ni] = mfma16(af[mi], bf[ni], acc[mi][ni]);
    }

    // epilogue: C/D layout  col = l15 (n), row = quad*4 + reg (o)
    for (int mi = 0; mi < 4; mi++) {
        int oRow = oBase + wy * 64 + mi * 16 + quad * 4;
        for (int ni = 0; ni < 4; ni++) {
            int n = nBase + wx * 64 + ni * 16 + l15;
            for (int reg = 0; reg < 4; reg++) {
                int oo = oRow + reg;
                float val = acc[mi][ni][reg] + pb[oo];
                int sel = oo >> 9, h = (oo >> 6) & 7, d = oo & 63;
                if (sel < 2)
                    qk[((((size_t)b * 2 + sel) * 8 + h) * 1024 + n) * 64 + d] = (f16)val;
                else
                    v[(((size_t)b * 8 + h) * 64 + d) * 1024 + n] = (f16)val;
            }
        }
    }
}

// ---------------------------------------------------------------------------
// Kernel 4: fused flash attention + residual.
//   grid (16 q-tiles, 64 bh).  Block: 4 waves; wave handles 16 q rows.
//   S = Qn . Kn^T  (Qn[n][d], Kn[n][d]);   O = P . V^T  (V[d][n]).
// ---------------------------------------------------------------------------
#define LDK 72  // 64 + 8 pad (f16 elems)
__global__ __launch_bounds__(256) void attn_k(const f16* __restrict__ qk,
                                              const f16* __restrict__ vg,
                                              const float* __restrict__ x,
                                              float* __restrict__ out) {
    __shared__ f16 lK[64 * LDK];
    __shared__ f16 lV[64 * LDK];
    __shared__ f16 lP[4][16 * LDK];

    int bh = blockIdx.y;
    int b = bh >> 3, h = bh & 7;
    int qBase = blockIdx.x * 64;
    int tid = threadIdx.x, lane = tid & 63, warp = tid >> 6;
    int quad = lane >> 4, l15 = lane & 15;

    const f16* qbase = qk + (((size_t)b * 2 + 0) * 8 + h) * 1024 * 64;
    const f16* kbase = qk + (((size_t)b * 2 + 1) * 8 + h) * 1024 * 64;
    const f16* vbase = vg + ((size_t)b * 8 + h) * 64 * 1024;

    int q0 = qBase + warp * 16;
    f16x8 aq[2];
    for (int kh = 0; kh < 2; kh++)
        aq[kh] = *(const f16x8*)&qbase[(size_t)(q0 + l15) * 64 + kh * 32 + quad * 8];

    f32x4 accO[4] = {};
    float m_r[4], l_r[4];
    for (int r = 0; r < 4; r++) { m_r[r] = -1e30f; l_r[r] = 0.f; }
    const float scale = 0.125f;  // 1/sqrt(64)

    for (int kt = 0; kt < 16; kt++) {
        __syncthreads();
        for (int c = tid; c < 512; c += 256) {
            int row = c >> 3, col = (c & 7) * 8;
            *(f16x8*)&lK[row * LDK + col] =
                *(const f16x8*)&kbase[(size_t)(kt * 64 + row) * 64 + col];
            *(f16x8*)&lV[row * LDK + col] =
                *(const f16x8*)&vbase[(size_t)row * 1024 + kt * 64 + col];
        }
        __syncthreads();

        // S tiles: 16 q x 64 kn
        f32x4 s[4] = {};
        for (int nt = 0; nt < 4; nt++)
            for (int kh = 0; kh < 2; kh++) {
                f16x8 bk = *(f16x8*)&lK[(nt * 16 + l15) * LDK + kh * 32 + quad * 8];
                s[nt] = mfma16(aq[kh], bk, s[nt]);
            }
        for (int nt = 0; nt < 4; nt++) s[nt] = s[nt] * scale;

        // online softmax per row (row = quad*4 + r, replicated across 16 lanes)
        float alpha[4];
        float ps[4][4];
        for (int r = 0; r < 4; r++) {
            float mx = -1e30f;
            for (int nt = 0; nt < 4; nt++) mx = fmaxf(mx, s[nt][r]);
            for (int off = 8; off; off >>= 1) mx = fmaxf(mx, __shfl_xor(mx, off, 64));
            float mn = fmaxf(m_r[r], mx);
            alpha[r] = __expf(m_r[r] - mn);
            m_r[r] = mn;
            float rs = 0.f;
            for (int nt = 0; nt < 4; nt++) {
                float p = __expf(s[nt][r] - mn);
                ps[nt][r] = p;
                rs += p;
            }
            for (int off = 8; off; off >>= 1) rs += __shfl_xor(rs, off, 64);
            l_r[r] = l_r[r] * alpha[r] + rs;
        }
        // rescale O, store P to per-wave LDS in A-operand-friendly layout
        for (int dt = 0; dt < 4; dt++)
            for (int r = 0; r < 4; r++) accO[dt][r] *= alpha[r];
        for (int nt = 0; nt < 4; nt++)
            for (int r = 0; r < 4; r++)
                lP[warp][(quad * 4 + r) * LDK + nt * 16 + l15] = (f16)ps[nt][r];
        __syncthreads();

        // PV: O[q][d] += P[q][kn] * V^T[kn][d]
        f16x8 ap[2];
        for (int kh = 0; kh < 2; kh++)
            ap[kh] = *(f16x8*)&lP[warp][l15 * LDK + kh * 32 + quad * 8];
        for (int dt = 0; dt < 4; dt++)
            for (int kh = 0; kh < 2; kh++) {
                f16x8 bv = *(f16x8*)&lV[(dt * 16 + l15) * LDK + kh * 32 + quad * 8];
                accO[dt] = mfma16(ap[kh], bv, accO[dt]);
            }
    }

    // epilogue: O[row=q][col=d] / l + residual;  rows quad*4+reg are contiguous qn
    for (int dt = 0; dt < 4; dt++) {
        int d = dt * 16 + l15;
        int qn = q0 + quad * 4;
        size_t idx = ((size_t)b * 512 + h * 64 + d) * 1024 + qn;
        float4 xv = *(const float4*)&x[idx];
        float4 o4;
        o4.x = xv.x + accO[dt][0] / l_r[0];
        o4.y = xv.y + accO[dt][1] / l_r[1];
        o4.z = xv.z + accO[dt][2] / l_r[2];
        o4.w = xv.w + accO[dt][3] / l_r[3];
        *(float4*)&out[idx] = o4;
    }
}

// ---------------------------------------------------------------------------
extern "C" void kernel_launch(void* const* d_in, const int* in_sizes, int n_in,
                              void* d_out, int out_size, void* d_ws, size_t ws_size,
                              hipStream_t stream) {
    (void)in_sizes; (void)n_in; (void)out_size; (void)ws_size;
    const float* x  = (const float*)d_in[0];
    const float* pv = (const float*)d_in[1];
    const float* pg = (const float*)d_in[2];
    const float* pb = (const float*)d_in[3];
    float* out = (float*)d_out;

    char* ws = (char*)d_ws;
    f16* w   = (f16*)(ws);                                   // 1,572,864 B
    f16* xT  = (f16*)(ws + 1572864);                         // 8,388,608 B
    f16* qk  = (f16*)(ws + 1572864 + 8388608);               // 16,777,216 B
    f16* v   = (f16*)(ws + 1572864 + 8388608 + 16777216);    // 8,388,608 B

    hipLaunchKernelGGL(compute_w_k,  dim3(1536),      dim3(256),   0, stream, pv, pg, w);
    hipLaunchKernelGGL(transpose_x_k, dim3(32, 16, 8), dim3(32, 8), 0, stream, x, xT);
    hipLaunchKernelGGL(qkv_gemm_k,   dim3(8, 12, 8),  dim3(256),   0, stream, w, xT, pb, qk, v);
    hipLaunchKernelGGL(attn_k,       dim3(16, 64),    dim3(256),   0, stream, qk, v, x, out);
}

// Round 2
// 153.129 us; speedup vs baseline: 1.1666x; 1.1666x over previous
//
#include <hip/hip_runtime.h>

typedef _Float16 f16;
typedef _Float16 f16x4 __attribute__((ext_vector_type(4)));
typedef _Float16 f16x8 __attribute__((ext_vector_type(8)));
typedef float f32x4 __attribute__((ext_vector_type(4)));

__device__ inline f32x4 mfma16(f16x8 a, f16x8 b, f32x4 c) {
    return __builtin_amdgcn_mfma_f32_16x16x32_f16(a, b, c, 0, 0, 0);
}

// 8B-granular LDS helpers (rows padded to 68 f16 = 136 B: only 8B-aligned)
__device__ inline void st8(f16* p, f16x8 v) {
    *(f16x4*)p = __builtin_shufflevector(v, v, 0, 1, 2, 3);
    *(f16x4*)(p + 4) = __builtin_shufflevector(v, v, 4, 5, 6, 7);
}
__device__ inline f16x8 ld8(const f16* p) {
    f16x4 lo = *(const f16x4*)p;
    f16x4 hi = *(const f16x4*)(p + 4);
    return __builtin_shufflevector(lo, hi, 0, 1, 2, 3, 4, 5, 6, 7);
}

// ---------------------------------------------------------------------------
// Kernel 1: weight norm.  w[o,c] = g[o] * v[o,c] / ||v[o,:]||   (f16 output)
// ---------------------------------------------------------------------------
__global__ __launch_bounds__(256) void compute_w_k(const float* __restrict__ pv,
                                                   const float* __restrict__ pg,
                                                   f16* __restrict__ w) {
    int o = blockIdx.x;
    const float* row = pv + (size_t)o * 512;
    float s = 0.f;
    for (int c = threadIdx.x; c < 512; c += 256) { float t = row[c]; s += t * t; }
    for (int off = 32; off; off >>= 1) s += __shfl_down(s, off, 64);
    __shared__ float red[4];
    int lane = threadIdx.x & 63, wid = threadIdx.x >> 6;
    if (lane == 0) red[wid] = s;
    __syncthreads();
    float tot = red[0] + red[1] + red[2] + red[3];
    float scale = pg[o] * rsqrtf(tot);
    for (int c = threadIdx.x; c < 512; c += 256)
        w[(size_t)o * 512 + c] = (f16)(row[c] * scale);
}

// ---------------------------------------------------------------------------
// Kernel 2: transpose x (B,C,N) fp32 -> xT (B,N,C) f16, LDS 32x32 tiles
// ---------------------------------------------------------------------------
__global__ __launch_bounds__(256) void transpose_x_k(const float* __restrict__ x,
                                                     f16* __restrict__ xT) {
    __shared__ float t[32][33];
    int b = blockIdx.z, n0 = blockIdx.x * 32, c0 = blockIdx.y * 32;
    int tx = threadIdx.x, ty = threadIdx.y;  // 32 x 8
    const float* xb = x + (size_t)b * 512 * 1024;
    for (int i = 0; i < 4; i++)
        t[ty + 8 * i][tx] = xb[(size_t)(c0 + ty + 8 * i) * 1024 + n0 + tx];
    __syncthreads();
    f16* xTb = xT + (size_t)b * 1024 * 512;
    for (int i = 0; i < 4; i++)
        xTb[(size_t)(n0 + ty + 8 * i) * 512 + c0 + tx] = (f16)t[tx][ty + 8 * i];
}

// ---------------------------------------------------------------------------
// Kernel 3: QKV projection GEMM.  C[b][o,n] = sum_c w[o,c] * xT[b][n,c] + pb[o]
//   M=1536 (o), N=1024 (n), K=512 (c).  128x128x32 tiles, 4 waves, 64x64/wave.
//   Epilogue scatters:  sel<2 -> qk[b][sel][h][n][d] (q pre-scaled by 1/8),
//                       sel==2 -> v[b][h][d][n]
// ---------------------------------------------------------------------------
#define GLDA 40  // 32 + 8 pad (f16 elems)
__global__ __launch_bounds__(256) void qkv_gemm_k(const f16* __restrict__ w,
                                                  const f16* __restrict__ xT,
                                                  const float* __restrict__ pb,
                                                  f16* __restrict__ qk,
                                                  f16* __restrict__ v) {
    __shared__ f16 lA[128 * GLDA];
    __shared__ f16 lB[128 * GLDA];
    int b = blockIdx.z;
    int oBase = blockIdx.y * 128;
    int nBase = blockIdx.x * 128;
    const f16* xb = xT + (size_t)b * 1024 * 512;
    int tid = threadIdx.x;
    int lane = tid & 63, warp = tid >> 6;
    int wy = warp >> 1, wx = warp & 1;
    int quad = lane >> 4, l15 = lane & 15;

    f32x4 acc[4][4] = {};

    for (int k0 = 0; k0 < 512; k0 += 32) {
        __syncthreads();
        for (int c = tid; c < 512; c += 256) {
            int row = c >> 2, col = (c & 3) * 8;
            *(f16x8*)&lA[row * GLDA + col] =
                *(const f16x8*)&w[(size_t)(oBase + row) * 512 + k0 + col];
            *(f16x8*)&lB[row * GLDA + col] =
                *(const f16x8*)&xb[(size_t)(nBase + row) * 512 + k0 + col];
        }
        __syncthreads();
        f16x8 af[4], bf[4];
        for (int mi = 0; mi < 4; mi++)
            af[mi] = *(f16x8*)&lA[(wy * 64 + mi * 16 + l15) * GLDA + quad * 8];
        for (int ni = 0; ni < 4; ni++)
            bf[ni] = *(f16x8*)&lB[(wx * 64 + ni * 16 + l15) * GLDA + quad * 8];
        for (int mi = 0; mi < 4; mi++)
            for (int ni = 0; ni < 4; ni++)
                acc[mi][ni] = mfma16(af[mi], bf[ni], acc[mi][ni]);
    }

    // epilogue: C/D layout  col = l15 (n), row = quad*4 + reg (o)
    for (int mi = 0; mi < 4; mi++) {
        int oRow = oBase + wy * 64 + mi * 16 + quad * 4;
        for (int ni = 0; ni < 4; ni++) {
            int n = nBase + wx * 64 + ni * 16 + l15;
            for (int reg = 0; reg < 4; reg++) {
                int oo = oRow + reg;
                float val = acc[mi][ni][reg] + pb[oo];
                int sel = oo >> 9, h = (oo >> 6) & 7, d = oo & 63;
                if (sel == 0) val *= 0.125f;  // fold 1/sqrt(64) into q
                if (sel < 2)
                    qk[((((size_t)b * 2 + sel) * 8 + h) * 1024 + n) * 64 + d] = (f16)val;
                else
                    v[(((size_t)b * 8 + h) * 64 + d) * 1024 + n] = (f16)val;
            }
        }
    }
}

// ---------------------------------------------------------------------------
// Kernel 4: fused flash attention + residual, S^T formulation.
//   grid (16 q-tiles, 64 bh), 4 waves; wave owns 16 q rows (q = q0 + l15).
//   S^T[k][q] = K-frag (A) x Q-frag (B)  -> col=q=l15, row=k=quad*4+reg
//   softmax per q column: in-register 16-max/sum + 2 quad-shuffles each
//   O^T[d][q] = V-frag (A) x P-frag (B)  -> col=q=l15, row=d=quad*4+reg
//   epilogue: O^T -> LDS (overlay) -> float4 residual+store
// ---------------------------------------------------------------------------
#define ALDK 68  // 64 + 4 pad (f16) = 34 dwords: uniform-bank for b64 access
__global__ __launch_bounds__(256) void attn_k(const f16* __restrict__ qk,
                                              const f16* __restrict__ vg,
                                              const float* __restrict__ x,
                                              float* __restrict__ out) {
    __shared__ __align__(16) f16 smem[3 * 64 * ALDK];
    f16* lK = smem;                 // 64 x 68
    f16* lV = smem + 64 * ALDK;     // 64 x 68
    f16* lPb = smem + 2 * 64 * ALDK;  // 4 warps x 16 x 68
    float* OT = (float*)smem;       // overlay of lK+lV: 64 x 68 f32

    int bh = blockIdx.y;
    int b = bh >> 3, h = bh & 7;
    int qBase = blockIdx.x * 64;
    int tid = threadIdx.x, lane = tid & 63, warp = tid >> 6;
    int quad = lane >> 4, l15 = lane & 15;

    const f16* qbase = qk + (((size_t)b * 2 + 0) * 8 + h) * 1024 * 64;
    const f16* kbase = qk + (((size_t)b * 2 + 1) * 8 + h) * 1024 * 64;
    const f16* vbase = vg + ((size_t)b * 8 + h) * 64 * 1024;
    f16* lP = lPb + warp * 16 * ALDK;

    int q0 = qBase + warp * 16;
    f16x8 aq[2];
    for (int kh = 0; kh < 2; kh++)
        aq[kh] = *(const f16x8*)&qbase[(size_t)(q0 + l15) * 64 + kh * 32 + quad * 8];

    // staging addressing: c = tid + 256*i, i in {0,1}; row=c>>3, chunk=c&7
    int sr0 = tid >> 3, sc0 = (tid & 7) * 8;
    int sr1 = (tid + 256) >> 3, sc1 = sc0;

    f16x8 rK[2], rV[2];
    rK[0] = *(const f16x8*)&kbase[(size_t)sr0 * 64 + sc0];
    rK[1] = *(const f16x8*)&kbase[(size_t)sr1 * 64 + sc1];
    rV[0] = *(const f16x8*)&vbase[(size_t)sr0 * 1024 + sc0];
    rV[1] = *(const f16x8*)&vbase[(size_t)sr1 * 1024 + sc1];

    f32x4 accO[4] = {};
    float m_cur = -1e30f, l_cur = 0.f;

    for (int kt = 0; kt < 16; kt++) {
        __syncthreads();  // prior iter's lK/lV reads complete
        st8(&lK[sr0 * ALDK + sc0], rK[0]);
        st8(&lK[sr1 * ALDK + sc1], rK[1]);
        st8(&lV[sr0 * ALDK + sc0], rV[0]);
        st8(&lV[sr1 * ALDK + sc1], rV[1]);
        __syncthreads();
        if (kt < 15) {  // prefetch next tile; latency hides under compute
            const f16* kb = kbase + (size_t)(kt + 1) * 64 * 64;
            rK[0] = *(const f16x8*)&kb[(size_t)sr0 * 64 + sc0];
            rK[1] = *(const f16x8*)&kb[(size_t)sr1 * 64 + sc1];
            rV[0] = *(const f16x8*)&vbase[(size_t)sr0 * 1024 + (kt + 1) * 64 + sc0];
            rV[1] = *(const f16x8*)&vbase[(size_t)sr1 * 1024 + (kt + 1) * 64 + sc1];
        }

        // S^T tiles: 64 k x 16 q.  col=q=l15, row=k_local=mt*16+quad*4+reg
        f32x4 st[4] = {};
        for (int mt = 0; mt < 4; mt++)
            for (int kh = 0; kh < 2; kh++) {
                f16x8 ak = ld8(&lK[(mt * 16 + l15) * ALDK + kh * 32 + quad * 8]);
                st[mt] = mfma16(ak, aq[kh], st[mt]);
            }

        // online softmax: each lane owns 16 scores of one q column
        float mx = m_cur;
        for (int mt = 0; mt < 4; mt++)
            for (int r = 0; r < 4; r++) mx = fmaxf(mx, st[mt][r]);
        mx = fmaxf(mx, __shfl_xor(mx, 16, 64));
        mx = fmaxf(mx, __shfl_xor(mx, 32, 64));
        float alpha = __expf(m_cur - mx);
        m_cur = mx;
        float rs = 0.f;
        for (int mt = 0; mt < 4; mt++) {
            f16x4 pk;
            for (int r = 0; r < 4; r++) {
                float p = __expf(st[mt][r] - mx);
                rs += p;
                pk[r] = (f16)p;
            }
            // consecutive k per quad -> one 8B store
            *(f16x4*)&lP[l15 * ALDK + mt * 16 + quad * 4] = pk;
        }
        rs += __shfl_xor(rs, 16, 64);
        rs += __shfl_xor(rs, 32, 64);
        l_cur = l_cur * alpha + rs;
        for (int dt = 0; dt < 4; dt++) accO[dt] *= alpha;

        // PV: O^T[d][q] += V[d][k] * P^T[k][q]   (lP wave-local: no barrier)
        for (int kh = 0; kh < 2; kh++) {
            f16x8 bp = ld8(&lP[l15 * ALDK + kh * 32 + quad * 8]);
            for (int dt = 0; dt < 4; dt++) {
                f16x8 av = ld8(&lV[(dt * 16 + l15) * ALDK + kh * 32 + quad * 8]);
                accO[dt] = mfma16(av, bp, accO[dt]);
            }
        }
    }

    // epilogue: O^T/l -> LDS overlay [d][q], then coalesced residual+store
    __syncthreads();  // all waves done reading lK/lV before overlay write
    float rl = 1.0f / l_cur;
    for (int dt = 0; dt < 4; dt++)
        for (int r = 0; r < 4; r++)
            OT[(dt * 16 + quad * 4 + r) * ALDK + warp * 16 + l15] = accO[dt][r] * rl;
    __syncthreads();
    for (int i = 0; i < 4; i++) {
        int cid = tid + 256 * i;        // 0..1023
        int d = cid >> 4, qi = (cid & 15) * 4;
        float4 o4 = *(float4*)&OT[d * ALDK + qi];
        size_t gi = ((size_t)b * 512 + h * 64 + d) * 1024 + qBase + qi;
        float4 xv = *(const float4*)&x[gi];
        o4.x += xv.x; o4.y += xv.y; o4.z += xv.z; o4.w += xv.w;
        *(float4*)&out[gi] = o4;
    }
}

// ---------------------------------------------------------------------------
extern "C" void kernel_launch(void* const* d_in, const int* in_sizes, int n_in,
                              void* d_out, int out_size, void* d_ws, size_t ws_size,
                              hipStream_t stream) {
    (void)in_sizes; (void)n_in; (void)out_size; (void)ws_size;
    const float* x  = (const float*)d_in[0];
    const float* pv = (const float*)d_in[1];
    const float* pg = (const float*)d_in[2];
    const float* pb = (const float*)d_in[3];
    float* out = (float*)d_out;

    char* ws = (char*)d_ws;
    f16* w   = (f16*)(ws);                                   // 1,572,864 B
    f16* xT  = (f16*)(ws + 1572864);                         // 8,388,608 B
    f16* qk  = (f16*)(ws + 1572864 + 8388608);               // 16,777,216 B
    f16* v   = (f16*)(ws + 1572864 + 8388608 + 16777216);    // 8,388,608 B

    hipLaunchKernelGGL(compute_w_k,  dim3(1536),      dim3(256),   0, stream, pv, pg, w);
    hipLaunchKernelGGL(transpose_x_k, dim3(32, 16, 8), dim3(32, 8), 0, stream, x, xT);
    hipLaunchKernelGGL(qkv_gemm_k,   dim3(8, 12, 8),  dim3(256),   0, stream, w, xT, pb, qk, v);
    hipLaunchKernelGGL(attn_k,       dim3(16, 64),    dim3(256),   0, stream, qk, v, x, out);
}